// Round 3
// baseline (241.572 us; speedup 1.0000x reference)
//
#include <hip/hip_runtime.h>
#include <hip/hip_bf16.h>
#include <math.h>

#define BB 8
#define NN 512
#define DD 512
#define NH 16
#define DH 32
#define TD 1536
#define NG 32
#define MAXD 128

typedef __attribute__((ext_vector_type(8))) short bf16x8;
typedef __attribute__((ext_vector_type(4))) float f32x4;
typedef __attribute__((ext_vector_type(2))) unsigned int u32x2;
typedef __attribute__((ext_vector_type(4))) unsigned int u32x4;

__device__ inline short f2bf(float x) {
    __hip_bfloat16 h = __float2bfloat16(x);
    return *reinterpret_cast<short*>(&h);
}
__device__ inline float bf2f(short x) {
    union { unsigned u; float f; } c;
    c.u = ((unsigned)(unsigned short)x) << 16;
    return c.f;
}
// v_cvt_pk_bf16_f32: lo16 <- src0, hi16 <- src1 (RNE). No builtin on gfx950.
__device__ inline unsigned cvt_pk_bf16(float lo, float hi) {
    unsigned r;
    asm("v_cvt_pk_bf16_f32 %0, %1, %2" : "=v"(r) : "v"(lo), "v"(hi));
    return r;
}
__device__ inline float exp2fast(float x) {  // D = 2^S0
    float r;
    asm("v_exp_f32 %0, %1" : "=v"(r) : "v"(x));
    return r;
}

// async 16B global->LDS. lds dest must be WAVE-UNIFORM base; lane i lands at base + i*16.
__device__ inline void gld_lds16(const void* g, void* l) {
    __builtin_amdgcn_global_load_lds(
        (const __attribute__((address_space(1))) unsigned int*)g,
        (__attribute__((address_space(3))) unsigned int*)l, 16, 0, 0);
}

// ------- weight fp32 -> bf16 convert (4 arrays) + fused RBF bias table ------
// Table: 193 nodes on [0,20] (nearest-neighbor lookup; |f'|*delta/2 ~ 3e-3).
// Tg is pre-scaled by log2(e): attention softmax runs in exp2 domain.
__global__ __launch_bounds__(256) void cvt_weights(
    const float* __restrict__ s0, const float* __restrict__ s1,
    const float* __restrict__ s2, const float* __restrict__ s3,
    short* __restrict__ d0, short* __restrict__ d1,
    short* __restrict__ d2, short* __restrict__ d3,
    const float* __restrict__ rbfw, const float* __restrict__ rbfb,
    short* __restrict__ Tg,
    int n0, int n1, int n2, int n3) {
    if (blockIdx.y == 4) {
        if (blockIdx.x != 0) return;
        const float STEP  = 20.0f / 31.0f;
        const float COEFF = -0.5f / (STEP * STEP);
        for (int idx = threadIdx.x; idx < 194 * 16; idx += 256) {
            const int i = idx >> 4, h = idx & 15;
            const float x = fminf((float)i, 192.0f) * (20.0f / 192.0f);
            float acc = rbfb[h];
#pragma unroll
            for (int g = 0; g < NG; g++) {
                const float t = x - (float)g * STEP;
                acc += __expf(COEFF * t * t) * rbfw[h * NG + g];
            }
            Tg[idx] = f2bf(acc * 1.44269504088896f);
        }
        return;
    }
    const float* s; short* d; int n;
    switch (blockIdx.y) {
        case 0: s = s0; d = d0; n = n0; break;
        case 1: s = s1; d = d1; n = n1; break;
        case 2: s = s2; d = d2; n = n2; break;
        default: s = s3; d = d3; n = n3; break;
    }
    const int i = (blockIdx.x * 256 + threadIdx.x) * 8;
    if (i >= n) return;
    const float4 a = *(const float4*)(s + i);
    const float4 b = *(const float4*)(s + i + 4);
    u32x4 o;
    o[0] = cvt_pk_bf16(a.x, a.y);
    o[1] = cvt_pk_bf16(a.z, a.w);
    o[2] = cvt_pk_bf16(b.x, b.y);
    o[3] = cvt_pk_bf16(b.z, b.w);
    *(u32x4*)(d + i) = o;
}

// ---------------- LayerNorm: bf16 out (float2 loads, packed stores) --------
__global__ __launch_bounds__(256) void ln_kernel(const float* __restrict__ x,
                                                 const float* __restrict__ g,
                                                 const float* __restrict__ b,
                                                 short* __restrict__ out_bf) {
    const int row = blockIdx.x;
    const int tid = threadIdx.x;
    const int wave = tid >> 6, lane = tid & 63;
    const float* xr = x + (size_t)row * DD;
    const float2 v01 = *(const float2*)(xr + 2 * tid);
    float s = v01.x + v01.y, q = v01.x * v01.x + v01.y * v01.y;
#pragma unroll
    for (int m = 1; m < 64; m <<= 1) { s += __shfl_xor(s, m); q += __shfl_xor(q, m); }
    __shared__ float ps[8];
    if (lane == 0) { ps[wave] = s; ps[wave + 4] = q; }
    __syncthreads();
    s = ps[0] + ps[1] + ps[2] + ps[3];
    q = ps[4] + ps[5] + ps[6] + ps[7];
    const float mean = s * (1.0f / DD);
    const float var  = q * (1.0f / DD) - mean * mean;
    const float rs   = rsqrtf(var + 1e-5f);
    const float2 g2 = *(const float2*)(g + 2 * tid);
    const float2 b2 = *(const float2*)(b + 2 * tid);
    const float o0 = (v01.x - mean) * rs * g2.x + b2.x;
    const float o1 = (v01.y - mean) * rs * g2.y + b2.y;
    *(unsigned*)&out_bf[(size_t)row * DD + 2 * tid] = cvt_pk_bf16(o0, o1);
}

// ------- bf16 MFMA GEMM, double-buffered: C = A @ W^T + bias (+gelu)(+res) --
// RESMODE: 0 = none, 1 = fp32 residual, 2 = bf16 residual
// Operand-SWAPPED mfma (bfr, af): lane's 4 acc regs = 4 CONSECUTIVE COLUMNS
// of one row -> vectorized 8B/16B C-stores instead of 64 scalar stores.
template <int TM, bool GELU, int RESMODE, bool OUTBF>
__global__ __launch_bounds__(256) void gemm_bf16(
    const short* __restrict__ A, const short* __restrict__ Bw,
    const float* __restrict__ bias, const void* __restrict__ res,
    void* __restrict__ Cout, int M, int Nout, int K) {
    const int MI = (TM >= 32) ? TM / 32 : 1;
    const int bm = blockIdx.y * TM;
    const int bn = blockIdx.x * 128;
    const int tid  = threadIdx.x;
    const int wave = tid >> 6;
    const int lane = tid & 63;
    const int l16  = lane & 15;
    const int quad = lane >> 4;
    const int wr = (wave >> 1) * (TM / 2);
    const int wc = (wave & 1) * 64;

    __shared__ short As[2][TM * 32];
    __shared__ short Bs[2][128 * 32];

    f32x4 acc[MI][4];
#pragma unroll
    for (int i = 0; i < MI; i++)
#pragma unroll
        for (int j = 0; j < 4; j++) acc[i][j] = (f32x4){0.f, 0.f, 0.f, 0.f};

    auto stage = [&](int buf, int k0) {
        const short* Ab = A + (size_t)bm * K + k0;
        const short* Bb = Bw + (size_t)bn * K + k0;
        if (TM >= 64) {
#pragma unroll
            for (int j = 0; j < TM / 64; j++) {
                const int idx = j * 256 + tid;
                gld_lds16(Ab + (size_t)(idx >> 2) * K + (idx & 3) * 8,
                          &As[buf][(size_t)(j * 256 + wave * 64) * 8]);
            }
        } else {  // TM == 32: 128 lanes (waves 0,1), wave-uniform branch
            if (tid < 128)
                gld_lds16(Ab + (size_t)(tid >> 2) * K + (tid & 3) * 8,
                          &As[buf][(size_t)(wave * 64) * 8]);
        }
#pragma unroll
        for (int j = 0; j < 2; j++) {
            const int idx = j * 256 + tid;
            gld_lds16(Bb + (size_t)(idx >> 2) * K + (idx & 3) * 8,
                      &Bs[buf][(size_t)(j * 256 + wave * 64) * 8]);
        }
    };
    auto compute = [&](int buf) {
        bf16x8 af[MI], bfr[4];
#pragma unroll
        for (int i = 0; i < MI; i++)
            af[i] = *(const bf16x8*)&As[buf][(wr + i * 16 + l16) * 32 + quad * 8];
#pragma unroll
        for (int j = 0; j < 4; j++)
            bfr[j] = *(const bf16x8*)&Bs[buf][(wc + j * 16 + l16) * 32 + quad * 8];
#pragma unroll
        for (int i = 0; i < MI; i++)
#pragma unroll
            for (int j = 0; j < 4; j++)
                acc[i][j] = __builtin_amdgcn_mfma_f32_16x16x32_bf16(bfr[j], af[i], acc[i][j], 0, 0, 0);
    };

    stage(0, 0);
    __syncthreads();
    int cur = 0;
    for (int k0 = 32; k0 < K; k0 += 32) {
        stage(cur ^ 1, k0);
        compute(cur);
        __syncthreads();
        cur ^= 1;
    }
    compute(cur);

    // epilogue: acc[i][j][r] = C[bm+wr+i*16+l16][bn+wc+j*16+quad*4+r]
#pragma unroll
    for (int i = 0; i < MI; i++) {
        const int row = bm + wr + i * 16 + l16;
#pragma unroll
        for (int j = 0; j < 4; j++) {
            const int col = bn + wc + j * 16 + quad * 4;
            const float4 b4 = *(const float4*)&bias[col];
            float v[4] = {acc[i][j][0] + b4.x, acc[i][j][1] + b4.y,
                          acc[i][j][2] + b4.z, acc[i][j][3] + b4.w};
            if (GELU) {
#pragma unroll
                for (int r = 0; r < 4; r++)
                    v[r] = 0.5f * v[r] * (1.0f + erff(v[r] * 0.70710678118654752f));
            }
            if (RESMODE == 1) {
                const float4 r4 = *(const float4*)&((const float*)res)[(size_t)row * Nout + col];
                v[0] += r4.x; v[1] += r4.y; v[2] += r4.z; v[3] += r4.w;
            }
            if (RESMODE == 2) {
                const short4 r4 = *(const short4*)&((const short*)res)[(size_t)row * Nout + col];
                v[0] += bf2f(r4.x); v[1] += bf2f(r4.y); v[2] += bf2f(r4.z); v[3] += bf2f(r4.w);
            }
            if (OUTBF) {
                u32x2 o;
                o[0] = cvt_pk_bf16(v[0], v[1]);
                o[1] = cvt_pk_bf16(v[2], v[3]);
                *(u32x2*)&((short*)Cout)[(size_t)row * Nout + col] = o;
            } else {
                *(float4*)&((float*)Cout)[(size_t)row * Nout + col] =
                    (float4){v[0], v[1], v[2], v[3]};
            }
        }
    }
}

// ---------------- MFMA flash attention, NO split-K, 32-key chunks -----------
// (unchanged from round 2 — see notes there)
__global__ __launch_bounds__(512, 2) void attn_mfma(
    const short* __restrict__ qkv,
    const int* __restrict__ dist,
    const float* __restrict__ dist3d,
    const float* __restrict__ demb,
    const short* __restrict__ Tg,
    short* __restrict__ Obf) {         // [4096][512] bf16 normalized
    const int blk  = blockIdx.x;
    const int b    = blk & 7;
    const int q0   = (blk >> 3) * 16;
    const int tid  = threadIdx.x;
    const int wave = tid >> 6;
    const int lane = tid & 63;
    const int l16  = lane & 15;
    const int quad = lane >> 4;
    const int hh0  = wave * 2;

    __shared__ short Vc[2][NH * 1024];       // 64 KB dbuf: per head [32k][32d]
    __shared__ short Pb[16 * 512];           // 16 KB: per (wave,head) [32k][16q]
    __shared__ short Tt[194 * 18];           // rbf NN table (*log2e), pad 18
    __shared__ short Db[128 * 18];           // dist_emb (*log2e), pad 18
    __shared__ unsigned short Pk[512 * 16];  // 16 KB: [k][q] packed dc|(ii<<8)

    for (int i = tid; i < 194 * 16; i += 512) Tt[(i >> 4) * 18 + (i & 15)] = Tg[i];
    for (int i = tid; i < 128 * 16; i += 512)
        Db[(i >> 4) * 18 + (i & 15)] = f2bf(demb[i] * 1.44269504088896f);
    {   // (dc, ii) precompute for all 16 q x 512 k, coalesced on k
        const size_t rb = ((size_t)(b * NN) + q0) * NN;
#pragma unroll
        for (int q = 0; q < 16; q++) {
            const size_t off = rb + (size_t)q * NN + tid;
            int dc = dist[off];
            dc = min(max(dc, 0), MAXD - 1);
            int ii = (int)(dist3d[off] * 9.6f + 0.5f);  // 192/20
            ii = min(ii, 192);
            Pk[tid * 16 + q] = (unsigned short)(dc | (ii << 8));
        }
    }

    const float scale = 0.17677669529663687f * 1.44269504088896f;  // /sqrt(32)*log2e
    bf16x8 qf[2];
#pragma unroll
    for (int h = 0; h < 2; h++)
        qf[h] = *(const bf16x8*)(qkv + (size_t)(b * NN + q0 + l16) * TD + (hh0 + h) * DH + quad * 8);

    f32x4 O[2][2];
    float lsum[2][4];
#pragma unroll
    for (int h = 0; h < 2; h++) {
#pragma unroll
        for (int tt = 0; tt < 2; tt++) O[h][tt] = (f32x4){0.f, 0.f, 0.f, 0.f};
#pragma unroll
        for (int r = 0; r < 4; r++) lsum[h][r] = 0.f;
    }

    __syncthreads();  // tables + Pk visible; the only barrier.

    const int sk = lane >> 2;
    const int sc = lane & 3;

    auto stageV = [&](int buf, int c) {
        const size_t rowb = (size_t)(b * NN + c * 32 + sk) * TD + 2 * DD + sc * 8;
#pragma unroll
        for (int h = 0; h < 2; h++) {
            short* dst = &Vc[buf][(hh0 + h) * 1024];
            gld_lds16(qkv + rowb + (hh0 + h) * DH, dst);
            gld_lds16(qkv + rowb + (size_t)16 * TD + (hh0 + h) * DH, dst + 512);
        }
    };
    auto loadK = [&](int c, bf16x8 (*kd)[2]) {
#pragma unroll
        for (int h = 0; h < 2; h++) {
            const short* base =
                qkv + (size_t)(b * NN + c * 32 + l16) * TD + DD + (hh0 + h) * DH + quad * 8;
            kd[h][0] = *(const bf16x8*)base;
            kd[h][1] = *(const bf16x8*)(base + 16 * TD);
        }
    };

    bf16x8 kf[2][2], kfn[2][2];
    stageV(0, 0);
    loadK(0, kf);
    int cur = 0;

    for (int c = 0; c < 16; c++) {  // 16 chunks of 32 keys
        asm volatile("" ::: "memory");
        __builtin_amdgcn_s_waitcnt(0x0F70);  // vmcnt(0): V(c) in LDS, kf(c) in regs
        asm volatile("" ::: "memory");

        // V tr reads for chunk c (only need Vc[cur]) — issue early
        u32x2 vraw[2][4];
#pragma unroll
        for (int h = 0; h < 2; h++) {
            const unsigned va =
                (unsigned)(uintptr_t)&Vc[cur][(hh0 + h) * 1024 + quad * 128 + l16];
            asm volatile("ds_read_b64_tr_b16 %0, %1 offset:0"    : "=v"(vraw[h][0]) : "v"(va));
            asm volatile("ds_read_b64_tr_b16 %0, %1 offset:128"  : "=v"(vraw[h][1]) : "v"(va));
            asm volatile("ds_read_b64_tr_b16 %0, %1 offset:1024" : "=v"(vraw[h][2]) : "v"(va));
            asm volatile("ds_read_b64_tr_b16 %0, %1 offset:1152" : "=v"(vraw[h][3]) : "v"(va));
        }

        if (c + 1 < 16) {  // prefetch a full chunk ahead
            stageV(cur ^ 1, c + 1);
            loadK(c + 1, kfn);
        }

        // ---- QK^T + bias + exp2 softmax, both 16-key halves ----
#pragma unroll
        for (int half = 0; half < 2; half++) {
            const ushort4 pk4 =
                *(const ushort4*)&Pk[(unsigned)((c * 32 + half * 16 + l16) * 16 + quad * 4)];
            const unsigned short pe[4] = {pk4.x, pk4.y, pk4.z, pk4.w};
            float bb[2][4];
#pragma unroll
            for (int r = 0; r < 4; r++) {
                const unsigned u  = pe[r];
                const unsigned dc = u & 0xFFu;
                const unsigned ii = u >> 8;
                const unsigned du = *(const unsigned*)&Db[dc * 18 + hh0];
                const unsigned tu = *(const unsigned*)&Tt[ii * 18 + hh0];
                union { unsigned x; float f; } a0, a1, b0, b1;
                a0.x = du << 16; a1.x = du & 0xFFFF0000u;
                b0.x = tu << 16; b1.x = tu & 0xFFFF0000u;
                bb[0][r] = a0.f + b0.f;
                bb[1][r] = a1.f + b1.f;
            }
#pragma unroll
            for (int h = 0; h < 2; h++) {
                f32x4 s = __builtin_amdgcn_mfma_f32_16x16x32_bf16(
                    qf[h], kf[h][half], (f32x4){0.f, 0.f, 0.f, 0.f}, 0, 0, 0);
                float pv[4];
#pragma unroll
                for (int r = 0; r < 4; r++) {
                    float sv = s[r] * scale + bb[h][r];
                    sv = fminf(sv, 28.853901f);  // 20*log2e
                    pv[r] = exp2fast(sv);
                    lsum[h][r] += pv[r];
                }
                u32x2 w;
                w[0] = cvt_pk_bf16(pv[0], pv[1]);
                w[1] = cvt_pk_bf16(pv[2], pv[3]);
                // S^T: Pb[k][q], k = half*16+l16, q = quad*4..+3 (contiguous)
                *(u32x2*)&Pb[(wave * 2 + h) * 512 + (half * 16 + l16) * 16 + quad * 4] = w;
            }
        }

        asm volatile("" ::: "memory");
        asm volatile("s_waitcnt lgkmcnt(0)" ::: "memory");  // Pb writes + vraw done
        __builtin_amdgcn_sched_barrier(0);

        // P A-fragments: tr-read of [32k][16q] tile; k-map matches V's
        u32x2 praw[2][2];
#pragma unroll
        for (int h = 0; h < 2; h++) {
            const unsigned pa =
                (unsigned)(uintptr_t)&Pb[(wave * 2 + h) * 512 + quad * 64 + l16];
            asm volatile("ds_read_b64_tr_b16 %0, %1 offset:0"   : "=v"(praw[h][0]) : "v"(pa));
            asm volatile("ds_read_b64_tr_b16 %0, %1 offset:512" : "=v"(praw[h][1]) : "v"(pa));
        }
        asm volatile("s_waitcnt lgkmcnt(0)" ::: "memory");
        __builtin_amdgcn_sched_barrier(0);

        __builtin_amdgcn_s_setprio(1);
#pragma unroll
        for (int h = 0; h < 2; h++) {
            union { u32x4 u; bf16x8 s; } pf, v0, v1;
            pf.u = (u32x4){praw[h][0][0], praw[h][0][1], praw[h][1][0], praw[h][1][1]};
#pragma unroll
            for (int r = 0; r < 4; r++) {
                v0.u[r] = __builtin_amdgcn_perm(vraw[h][r][1], vraw[h][r][0], 0x05040100u);
                v1.u[r] = __builtin_amdgcn_perm(vraw[h][r][1], vraw[h][r][0], 0x07060302u);
            }
            O[h][0] = __builtin_amdgcn_mfma_f32_16x16x32_bf16(pf.s, v0.s, O[h][0], 0, 0, 0);
            O[h][1] = __builtin_amdgcn_mfma_f32_16x16x32_bf16(pf.s, v1.s, O[h][1], 0, 0, 0);
        }
        __builtin_amdgcn_s_setprio(0);

#pragma unroll
        for (int h = 0; h < 2; h++) { kf[h][0] = kfn[h][0]; kf[h][1] = kfn[h][1]; }
        cur ^= 1;
    }

    // epilogue: reduce lsum over the 16-lane group, normalize, write bf16 O
#pragma unroll
    for (int h = 0; h < 2; h++) {
        const int hh = hh0 + h;
#pragma unroll
        for (int m = 1; m < 16; m <<= 1)
#pragma unroll
            for (int r = 0; r < 4; r++) lsum[h][r] += __shfl_xor(lsum[h][r], m);
#pragma unroll
        for (int r = 0; r < 4; r++) {
            const float rl = 1.0f / lsum[h][r];
            const size_t row = (size_t)(b * NN + q0 + quad * 4 + r);
#pragma unroll
            for (int tt = 0; tt < 2; tt++)
                Obf[row * DD + hh * DH + tt * 16 + l16] = f2bf(O[h][tt][r] * rl);
        }
    }
}

extern "C" void kernel_launch(void* const* d_in, const int* in_sizes, int n_in,
                              void* d_out, int out_size, void* d_ws, size_t ws_size,
                              hipStream_t stream) {
    const float* x      = (const float*)d_in[0];
    const int*   dist   = (const int*)d_in[1];
    const float* dist3d = (const float*)d_in[2];
    const float* n1g    = (const float*)d_in[3];
    const float* n1b    = (const float*)d_in[4];
    const float* win    = (const float*)d_in[5];
    const float* bin    = (const float*)d_in[6];
    const float* wo     = (const float*)d_in[7];
    const float* bo     = (const float*)d_in[8];
    const float* demb   = (const float*)d_in[9];
    const float* rbfw   = (const float*)d_in[10];
    const float* rbfb   = (const float*)d_in[11];
    const float* n2g    = (const float*)d_in[12];
    const float* n2b    = (const float*)d_in[13];
    const float* w1     = (const float*)d_in[14];
    const float* b1     = (const float*)d_in[15];
    const float* w2     = (const float*)d_in[16];
    const float* b2     = (const float*)d_in[17];

    // workspace. o_bf region is reused by mid_bf (ffn1 output) since o_bf is
    // dead after the out-projection, which runs before ffn1.
    char* p = (char*)d_ws;
    short* h_bf   = (short*)p; p += (size_t)4096 * 512 * 2;
    short* qkv_bf = (short*)p; p += (size_t)4096 * 1536 * 2;
    float* hres   = (float*)p; p += (size_t)4096 * 512 * 4;
    short* h2_bf  = (short*)p; p += (size_t)4096 * 512 * 2;
    short* win_bf = (short*)p; p += (size_t)1536 * 512 * 2;
    short* wo_bf  = (short*)p; p += (size_t)512 * 512 * 2;
    short* w1_bf  = (short*)p; p += (size_t)2048 * 512 * 2;
    short* w2_bf  = (short*)p; p += (size_t)512 * 2048 * 2;
    short* Tg     = (short*)p; p += (size_t)8192;  // 194*16 bf16 = 6208 B
    short* o_bf   = (short*)p;
    short* mid_bf = (short*)p;  // overlays o_bf region
    p += (size_t)4096 * 2048 * 2;

    const int M = BB * NN;  // 4096

    cvt_weights<<<dim3(512, 5), 256, 0, stream>>>(
        win, wo, w1, w2, win_bf, wo_bf, w1_bf, w2_bf, rbfw, rbfb, Tg,
        1536 * 512, 512 * 512, 2048 * 512, 512 * 2048);
    ln_kernel<<<M, 256, 0, stream>>>(x, n1g, n1b, h_bf);
    // qkv: TM=64 -> 768 wgs = 3/CU exact (was 384 = 1.5/CU)
    gemm_bf16<64, false, 0, true><<<dim3(12, 64), 256, 0, stream>>>(
        h_bf, win_bf, bin, nullptr, qkv_bf, M, TD, DD);
    attn_mfma<<<256, 512, 0, stream>>>(
        qkv_bf, dist, dist3d, demb, Tg, o_bf);
    // out-proj: TM=32 -> 512 wgs = 2/CU (was 256 = 1/CU)
    gemm_bf16<32, false, 2, false><<<dim3(4, 128), 256, 0, stream>>>(
        o_bf, wo_bf, bo, h_bf, hres, M, DD, DD);
    ln_kernel<<<M, 256, 0, stream>>>(hres, n2g, n2b, h2_bf);
    gemm_bf16<128, true, 0, true><<<dim3(16, 32), 256, 0, stream>>>(
        h2_bf, w1_bf, b1, nullptr, mid_bf, M, 2048, DD);
    // ffn2: TM=32 -> 512 wgs = 2/CU over the K=2048 loop (was 256 = 1/CU)
    gemm_bf16<32, false, 1, false><<<dim3(4, 128), 256, 0, stream>>>(
        mid_bf, w2_bf, b2, hres, (float*)d_out, M, DD, 2048);
}

// Round 4
// 237.801 us; speedup vs baseline: 1.0159x; 1.0159x over previous
//
#include <hip/hip_runtime.h>
#include <hip/hip_bf16.h>
#include <math.h>

#define BB 8
#define NN 512
#define DD 512
#define NH 16
#define DH 32
#define TD 1536
#define NG 32
#define MAXD 128

typedef __attribute__((ext_vector_type(8))) short bf16x8;
typedef __attribute__((ext_vector_type(4))) float f32x4;
typedef __attribute__((ext_vector_type(2))) unsigned int u32x2;
typedef __attribute__((ext_vector_type(4))) unsigned int u32x4;

__device__ inline short f2bf(float x) {
    __hip_bfloat16 h = __float2bfloat16(x);
    return *reinterpret_cast<short*>(&h);
}
__device__ inline float bf2f(short x) {
    union { unsigned u; float f; } c;
    c.u = ((unsigned)(unsigned short)x) << 16;
    return c.f;
}
// v_cvt_pk_bf16_f32: lo16 <- src0, hi16 <- src1 (RNE). No builtin on gfx950.
__device__ inline unsigned cvt_pk_bf16(float lo, float hi) {
    unsigned r;
    asm("v_cvt_pk_bf16_f32 %0, %1, %2" : "=v"(r) : "v"(lo), "v"(hi));
    return r;
}
__device__ inline float exp2fast(float x) {  // D = 2^S0
    float r;
    asm("v_exp_f32 %0, %1" : "=v"(r) : "v"(x));
    return r;
}

// async 16B global->LDS. lds dest must be WAVE-UNIFORM base; lane i lands at base + i*16.
__device__ inline void gld_lds16(const void* g, void* l) {
    __builtin_amdgcn_global_load_lds(
        (const __attribute__((address_space(1))) unsigned int*)g,
        (__attribute__((address_space(3))) unsigned int*)l, 16, 0, 0);
}

// ------- weight fp32 -> bf16 convert (4 arrays) + fused RBF bias table ------
// Table: 193 nodes on [0,20] (nearest-neighbor lookup; |f'|*delta/2 ~ 3e-3).
// Tg is pre-scaled by log2(e): attention softmax runs in exp2 domain.
__global__ __launch_bounds__(256) void cvt_weights(
    const float* __restrict__ s0, const float* __restrict__ s1,
    const float* __restrict__ s2, const float* __restrict__ s3,
    short* __restrict__ d0, short* __restrict__ d1,
    short* __restrict__ d2, short* __restrict__ d3,
    const float* __restrict__ rbfw, const float* __restrict__ rbfb,
    short* __restrict__ Tg,
    int n0, int n1, int n2, int n3) {
    if (blockIdx.y == 4) {
        if (blockIdx.x != 0) return;
        const float STEP  = 20.0f / 31.0f;
        const float COEFF = -0.5f / (STEP * STEP);
        for (int idx = threadIdx.x; idx < 194 * 16; idx += 256) {
            const int i = idx >> 4, h = idx & 15;
            const float x = fminf((float)i, 192.0f) * (20.0f / 192.0f);
            float acc = rbfb[h];
#pragma unroll
            for (int g = 0; g < NG; g++) {
                const float t = x - (float)g * STEP;
                acc += __expf(COEFF * t * t) * rbfw[h * NG + g];
            }
            Tg[idx] = f2bf(acc * 1.44269504088896f);
        }
        return;
    }
    const float* s; short* d; int n;
    switch (blockIdx.y) {
        case 0: s = s0; d = d0; n = n0; break;
        case 1: s = s1; d = d1; n = n1; break;
        case 2: s = s2; d = d2; n = n2; break;
        default: s = s3; d = d3; n = n3; break;
    }
    const int i = (blockIdx.x * 256 + threadIdx.x) * 8;
    if (i >= n) return;
    const float4 a = *(const float4*)(s + i);
    const float4 b = *(const float4*)(s + i + 4);
    u32x4 o;
    o[0] = cvt_pk_bf16(a.x, a.y);
    o[1] = cvt_pk_bf16(a.z, a.w);
    o[2] = cvt_pk_bf16(b.x, b.y);
    o[3] = cvt_pk_bf16(b.z, b.w);
    *(u32x4*)(d + i) = o;
}

// ---------------- LayerNorm: bf16 out (float2 loads, packed stores) --------
__global__ __launch_bounds__(256) void ln_kernel(const float* __restrict__ x,
                                                 const float* __restrict__ g,
                                                 const float* __restrict__ b,
                                                 short* __restrict__ out_bf) {
    const int row = blockIdx.x;
    const int tid = threadIdx.x;
    const int wave = tid >> 6, lane = tid & 63;
    const float* xr = x + (size_t)row * DD;
    const float2 v01 = *(const float2*)(xr + 2 * tid);
    float s = v01.x + v01.y, q = v01.x * v01.x + v01.y * v01.y;
#pragma unroll
    for (int m = 1; m < 64; m <<= 1) { s += __shfl_xor(s, m); q += __shfl_xor(q, m); }
    __shared__ float ps[8];
    if (lane == 0) { ps[wave] = s; ps[wave + 4] = q; }
    __syncthreads();
    s = ps[0] + ps[1] + ps[2] + ps[3];
    q = ps[4] + ps[5] + ps[6] + ps[7];
    const float mean = s * (1.0f / DD);
    const float var  = q * (1.0f / DD) - mean * mean;
    const float rs   = rsqrtf(var + 1e-5f);
    const float2 g2 = *(const float2*)(g + 2 * tid);
    const float2 b2 = *(const float2*)(b + 2 * tid);
    const float o0 = (v01.x - mean) * rs * g2.x + b2.x;
    const float o1 = (v01.y - mean) * rs * g2.y + b2.y;
    *(unsigned*)&out_bf[(size_t)row * DD + 2 * tid] = cvt_pk_bf16(o0, o1);
}

// ------- bf16 MFMA GEMM, double-buffered: C = A @ W^T + bias (+gelu)(+res) --
// RESMODE: 0 = none, 1 = fp32 residual, 2 = bf16 residual
// PARTIAL: split-K plane write (no bias/res), blockIdx.z = K-slice, loops Kloop.
// Operand-SWAPPED mfma (bfr, af): lane's 4 acc regs = 4 CONSECUTIVE COLUMNS
// of one row -> vectorized 8B/16B C-stores.
template <int TM, bool GELU, int RESMODE, bool OUTBF, bool PARTIAL>
__global__ __launch_bounds__(256) void gemm_bf16(
    const short* __restrict__ A, const short* __restrict__ Bw,
    const float* __restrict__ bias, const void* __restrict__ res,
    void* __restrict__ Cout, int M, int Nout, int K, int Kloop) {
    const int MI = (TM >= 32) ? TM / 32 : 1;
    const int bm = blockIdx.y * TM;
    const int bn = blockIdx.x * 128;
    const int kbase = PARTIAL ? blockIdx.z * Kloop : 0;
    const int tid  = threadIdx.x;
    const int wave = tid >> 6;
    const int lane = tid & 63;
    const int l16  = lane & 15;
    const int quad = lane >> 4;
    const int wr = (wave >> 1) * (TM / 2);
    const int wc = (wave & 1) * 64;

    __shared__ short As[2][TM * 32];
    __shared__ short Bs[2][128 * 32];

    f32x4 acc[MI][4];
#pragma unroll
    for (int i = 0; i < MI; i++)
#pragma unroll
        for (int j = 0; j < 4; j++) acc[i][j] = (f32x4){0.f, 0.f, 0.f, 0.f};

    auto stage = [&](int buf, int k0) {
        const short* Ab = A + (size_t)bm * K + kbase + k0;
        const short* Bb = Bw + (size_t)bn * K + kbase + k0;
        if (TM >= 64) {
#pragma unroll
            for (int j = 0; j < TM / 64; j++) {
                const int idx = j * 256 + tid;
                gld_lds16(Ab + (size_t)(idx >> 2) * K + (idx & 3) * 8,
                          &As[buf][(size_t)(j * 256 + wave * 64) * 8]);
            }
        } else {  // TM == 32: 128 lanes (waves 0,1), wave-uniform branch
            if (tid < 128)
                gld_lds16(Ab + (size_t)(tid >> 2) * K + (tid & 3) * 8,
                          &As[buf][(size_t)(wave * 64) * 8]);
        }
#pragma unroll
        for (int j = 0; j < 2; j++) {
            const int idx = j * 256 + tid;
            gld_lds16(Bb + (size_t)(idx >> 2) * K + (idx & 3) * 8,
                      &Bs[buf][(size_t)(j * 256 + wave * 64) * 8]);
        }
    };
    auto compute = [&](int buf) {
        bf16x8 af[MI], bfr[4];
#pragma unroll
        for (int i = 0; i < MI; i++)
            af[i] = *(const bf16x8*)&As[buf][(wr + i * 16 + l16) * 32 + quad * 8];
#pragma unroll
        for (int j = 0; j < 4; j++)
            bfr[j] = *(const bf16x8*)&Bs[buf][(wc + j * 16 + l16) * 32 + quad * 8];
#pragma unroll
        for (int i = 0; i < MI; i++)
#pragma unroll
            for (int j = 0; j < 4; j++)
                acc[i][j] = __builtin_amdgcn_mfma_f32_16x16x32_bf16(bfr[j], af[i], acc[i][j], 0, 0, 0);
    };

    stage(0, 0);
    __syncthreads();
    int cur = 0;
    for (int k0 = 32; k0 < Kloop; k0 += 32) {
        stage(cur ^ 1, k0);
        compute(cur);
        __syncthreads();
        cur ^= 1;
    }
    compute(cur);

    // epilogue: acc[i][j][r] = C[bm+wr+i*16+l16][bn+wc+j*16+quad*4+r]
    float* pout = PARTIAL
        ? (float*)Cout + (size_t)blockIdx.z * M * Nout
        : (float*)Cout;
#pragma unroll
    for (int i = 0; i < MI; i++) {
        const int row = bm + wr + i * 16 + l16;
#pragma unroll
        for (int j = 0; j < 4; j++) {
            const int col = bn + wc + j * 16 + quad * 4;
            float v[4] = {acc[i][j][0], acc[i][j][1], acc[i][j][2], acc[i][j][3]};
            if (!PARTIAL) {
                const float4 b4 = *(const float4*)&bias[col];
                v[0] += b4.x; v[1] += b4.y; v[2] += b4.z; v[3] += b4.w;
            }
            if (GELU) {
#pragma unroll
                for (int r = 0; r < 4; r++)
                    v[r] = 0.5f * v[r] * (1.0f + erff(v[r] * 0.70710678118654752f));
            }
            if (RESMODE == 1) {
                const float4 r4 = *(const float4*)&((const float*)res)[(size_t)row * Nout + col];
                v[0] += r4.x; v[1] += r4.y; v[2] += r4.z; v[3] += r4.w;
            }
            if (RESMODE == 2) {
                const short4 r4 = *(const short4*)&((const short*)res)[(size_t)row * Nout + col];
                v[0] += bf2f(r4.x); v[1] += bf2f(r4.y); v[2] += bf2f(r4.z); v[3] += bf2f(r4.w);
            }
            if (OUTBF) {
                u32x2 o;
                o[0] = cvt_pk_bf16(v[0], v[1]);
                o[1] = cvt_pk_bf16(v[2], v[3]);
                *(u32x2*)&((short*)Cout)[(size_t)row * Nout + col] = o;
            } else {
                *(float4*)&pout[(size_t)row * Nout + col] = (float4){v[0], v[1], v[2], v[3]};
            }
        }
    }
}

// ------- split-K combine: out = p0+p1+p2+p3 + bias + res (all fp32) --------
__global__ __launch_bounds__(256) void combine4(
    const float* __restrict__ p, const float* __restrict__ bias,
    const float* __restrict__ res, float* __restrict__ out) {
    const size_t PO = (size_t)4096 * 512;
    const size_t i = ((size_t)blockIdx.x * 256 + threadIdx.x) * 4;
    const float4 a = *(const float4*)(p + i);
    const float4 b = *(const float4*)(p + PO + i);
    const float4 c = *(const float4*)(p + 2 * PO + i);
    const float4 d = *(const float4*)(p + 3 * PO + i);
    const float4 r = *(const float4*)(res + i);
    const float4 bb = *(const float4*)&bias[i & 511];
    float4 o;
    o.x = a.x + b.x + c.x + d.x + r.x + bb.x;
    o.y = a.y + b.y + c.y + d.y + r.y + bb.y;
    o.z = a.z + b.z + c.z + d.z + r.z + bb.z;
    o.w = a.w + b.w + c.w + d.w + r.w + bb.w;
    *(float4*)(out + i) = o;
}

// ---------------- MFMA flash attention, NO split-K, 32-key chunks -----------
// (unchanged from round 2 — see notes there)
__global__ __launch_bounds__(512, 2) void attn_mfma(
    const short* __restrict__ qkv,
    const int* __restrict__ dist,
    const float* __restrict__ dist3d,
    const float* __restrict__ demb,
    const short* __restrict__ Tg,
    short* __restrict__ Obf) {         // [4096][512] bf16 normalized
    const int blk  = blockIdx.x;
    const int b    = blk & 7;
    const int q0   = (blk >> 3) * 16;
    const int tid  = threadIdx.x;
    const int wave = tid >> 6;
    const int lane = tid & 63;
    const int l16  = lane & 15;
    const int quad = lane >> 4;
    const int hh0  = wave * 2;

    __shared__ short Vc[2][NH * 1024];       // 64 KB dbuf: per head [32k][32d]
    __shared__ short Pb[16 * 512];           // 16 KB: per (wave,head) [32k][16q]
    __shared__ short Tt[194 * 18];           // rbf NN table (*log2e), pad 18
    __shared__ short Db[128 * 18];           // dist_emb (*log2e), pad 18
    __shared__ unsigned short Pk[512 * 16];  // 16 KB: [k][q] packed dc|(ii<<8)

    for (int i = tid; i < 194 * 16; i += 512) Tt[(i >> 4) * 18 + (i & 15)] = Tg[i];
    for (int i = tid; i < 128 * 16; i += 512)
        Db[(i >> 4) * 18 + (i & 15)] = f2bf(demb[i] * 1.44269504088896f);
    {   // (dc, ii) precompute for all 16 q x 512 k, coalesced on k
        const size_t rb = ((size_t)(b * NN) + q0) * NN;
#pragma unroll
        for (int q = 0; q < 16; q++) {
            const size_t off = rb + (size_t)q * NN + tid;
            int dc = dist[off];
            dc = min(max(dc, 0), MAXD - 1);
            int ii = (int)(dist3d[off] * 9.6f + 0.5f);  // 192/20
            ii = min(ii, 192);
            Pk[tid * 16 + q] = (unsigned short)(dc | (ii << 8));
        }
    }

    const float scale = 0.17677669529663687f * 1.44269504088896f;  // /sqrt(32)*log2e
    bf16x8 qf[2];
#pragma unroll
    for (int h = 0; h < 2; h++)
        qf[h] = *(const bf16x8*)(qkv + (size_t)(b * NN + q0 + l16) * TD + (hh0 + h) * DH + quad * 8);

    f32x4 O[2][2];
    float lsum[2][4];
#pragma unroll
    for (int h = 0; h < 2; h++) {
#pragma unroll
        for (int tt = 0; tt < 2; tt++) O[h][tt] = (f32x4){0.f, 0.f, 0.f, 0.f};
#pragma unroll
        for (int r = 0; r < 4; r++) lsum[h][r] = 0.f;
    }

    __syncthreads();  // tables + Pk visible; the only barrier.

    const int sk = lane >> 2;
    const int sc = lane & 3;

    auto stageV = [&](int buf, int c) {
        const size_t rowb = (size_t)(b * NN + c * 32 + sk) * TD + 2 * DD + sc * 8;
#pragma unroll
        for (int h = 0; h < 2; h++) {
            short* dst = &Vc[buf][(hh0 + h) * 1024];
            gld_lds16(qkv + rowb + (hh0 + h) * DH, dst);
            gld_lds16(qkv + rowb + (size_t)16 * TD + (hh0 + h) * DH, dst + 512);
        }
    };
    auto loadK = [&](int c, bf16x8 (*kd)[2]) {
#pragma unroll
        for (int h = 0; h < 2; h++) {
            const short* base =
                qkv + (size_t)(b * NN + c * 32 + l16) * TD + DD + (hh0 + h) * DH + quad * 8;
            kd[h][0] = *(const bf16x8*)base;
            kd[h][1] = *(const bf16x8*)(base + 16 * TD);
        }
    };

    bf16x8 kf[2][2], kfn[2][2];
    stageV(0, 0);
    loadK(0, kf);
    int cur = 0;

    for (int c = 0; c < 16; c++) {  // 16 chunks of 32 keys
        asm volatile("" ::: "memory");
        __builtin_amdgcn_s_waitcnt(0x0F70);  // vmcnt(0): V(c) in LDS, kf(c) in regs
        asm volatile("" ::: "memory");

        // V tr reads for chunk c (only need Vc[cur]) — issue early
        u32x2 vraw[2][4];
#pragma unroll
        for (int h = 0; h < 2; h++) {
            const unsigned va =
                (unsigned)(uintptr_t)&Vc[cur][(hh0 + h) * 1024 + quad * 128 + l16];
            asm volatile("ds_read_b64_tr_b16 %0, %1 offset:0"    : "=v"(vraw[h][0]) : "v"(va));
            asm volatile("ds_read_b64_tr_b16 %0, %1 offset:128"  : "=v"(vraw[h][1]) : "v"(va));
            asm volatile("ds_read_b64_tr_b16 %0, %1 offset:1024" : "=v"(vraw[h][2]) : "v"(va));
            asm volatile("ds_read_b64_tr_b16 %0, %1 offset:1152" : "=v"(vraw[h][3]) : "v"(va));
        }

        if (c + 1 < 16) {  // prefetch a full chunk ahead
            stageV(cur ^ 1, c + 1);
            loadK(c + 1, kfn);
        }

        // ---- QK^T + bias + exp2 softmax, both 16-key halves ----
#pragma unroll
        for (int half = 0; half < 2; half++) {
            const ushort4 pk4 =
                *(const ushort4*)&Pk[(unsigned)((c * 32 + half * 16 + l16) * 16 + quad * 4)];
            const unsigned short pe[4] = {pk4.x, pk4.y, pk4.z, pk4.w};
            float bb[2][4];
#pragma unroll
            for (int r = 0; r < 4; r++) {
                const unsigned u  = pe[r];
                const unsigned dc = u & 0xFFu;
                const unsigned ii = u >> 8;
                const unsigned du = *(const unsigned*)&Db[dc * 18 + hh0];
                const unsigned tu = *(const unsigned*)&Tt[ii * 18 + hh0];
                union { unsigned x; float f; } a0, a1, b0, b1;
                a0.x = du << 16; a1.x = du & 0xFFFF0000u;
                b0.x = tu << 16; b1.x = tu & 0xFFFF0000u;
                bb[0][r] = a0.f + b0.f;
                bb[1][r] = a1.f + b1.f;
            }
#pragma unroll
            for (int h = 0; h < 2; h++) {
                f32x4 s = __builtin_amdgcn_mfma_f32_16x16x32_bf16(
                    qf[h], kf[h][half], (f32x4){0.f, 0.f, 0.f, 0.f}, 0, 0, 0);
                float pv[4];
#pragma unroll
                for (int r = 0; r < 4; r++) {
                    float sv = s[r] * scale + bb[h][r];
                    sv = fminf(sv, 28.853901f);  // 20*log2e
                    pv[r] = exp2fast(sv);
                    lsum[h][r] += pv[r];
                }
                u32x2 w;
                w[0] = cvt_pk_bf16(pv[0], pv[1]);
                w[1] = cvt_pk_bf16(pv[2], pv[3]);
                // S^T: Pb[k][q], k = half*16+l16, q = quad*4..+3 (contiguous)
                *(u32x2*)&Pb[(wave * 2 + h) * 512 + (half * 16 + l16) * 16 + quad * 4] = w;
            }
        }

        asm volatile("" ::: "memory");
        asm volatile("s_waitcnt lgkmcnt(0)" ::: "memory");  // Pb writes + vraw done
        __builtin_amdgcn_sched_barrier(0);

        // P A-fragments: tr-read of [32k][16q] tile; k-map matches V's
        u32x2 praw[2][2];
#pragma unroll
        for (int h = 0; h < 2; h++) {
            const unsigned pa =
                (unsigned)(uintptr_t)&Pb[(wave * 2 + h) * 512 + quad * 64 + l16];
            asm volatile("ds_read_b64_tr_b16 %0, %1 offset:0"   : "=v"(praw[h][0]) : "v"(pa));
            asm volatile("ds_read_b64_tr_b16 %0, %1 offset:512" : "=v"(praw[h][1]) : "v"(pa));
        }
        asm volatile("s_waitcnt lgkmcnt(0)" ::: "memory");
        __builtin_amdgcn_sched_barrier(0);

        __builtin_amdgcn_s_setprio(1);
#pragma unroll
        for (int h = 0; h < 2; h++) {
            union { u32x4 u; bf16x8 s; } pf, v0, v1;
            pf.u = (u32x4){praw[h][0][0], praw[h][0][1], praw[h][1][0], praw[h][1][1]};
#pragma unroll
            for (int r = 0; r < 4; r++) {
                v0.u[r] = __builtin_amdgcn_perm(vraw[h][r][1], vraw[h][r][0], 0x05040100u);
                v1.u[r] = __builtin_amdgcn_perm(vraw[h][r][1], vraw[h][r][0], 0x07060302u);
            }
            O[h][0] = __builtin_amdgcn_mfma_f32_16x16x32_bf16(pf.s, v0.s, O[h][0], 0, 0, 0);
            O[h][1] = __builtin_amdgcn_mfma_f32_16x16x32_bf16(pf.s, v1.s, O[h][1], 0, 0, 0);
        }
        __builtin_amdgcn_s_setprio(0);

#pragma unroll
        for (int h = 0; h < 2; h++) { kf[h][0] = kfn[h][0]; kf[h][1] = kfn[h][1]; }
        cur ^= 1;
    }

    // epilogue: reduce lsum over the 16-lane group, normalize, write bf16 O
#pragma unroll
    for (int h = 0; h < 2; h++) {
        const int hh = hh0 + h;
#pragma unroll
        for (int m = 1; m < 16; m <<= 1)
#pragma unroll
            for (int r = 0; r < 4; r++) lsum[h][r] += __shfl_xor(lsum[h][r], m);
#pragma unroll
        for (int r = 0; r < 4; r++) {
            const float rl = 1.0f / lsum[h][r];
            const size_t row = (size_t)(b * NN + q0 + quad * 4 + r);
#pragma unroll
            for (int tt = 0; tt < 2; tt++)
                Obf[row * DD + hh * DH + tt * 16 + l16] = f2bf(O[h][tt][r] * rl);
        }
    }
}

extern "C" void kernel_launch(void* const* d_in, const int* in_sizes, int n_in,
                              void* d_out, int out_size, void* d_ws, size_t ws_size,
                              hipStream_t stream) {
    const float* x      = (const float*)d_in[0];
    const int*   dist   = (const int*)d_in[1];
    const float* dist3d = (const float*)d_in[2];
    const float* n1g    = (const float*)d_in[3];
    const float* n1b    = (const float*)d_in[4];
    const float* win    = (const float*)d_in[5];
    const float* bin    = (const float*)d_in[6];
    const float* wo     = (const float*)d_in[7];
    const float* bo     = (const float*)d_in[8];
    const float* demb   = (const float*)d_in[9];
    const float* rbfw   = (const float*)d_in[10];
    const float* rbfb   = (const float*)d_in[11];
    const float* n2g    = (const float*)d_in[12];
    const float* n2b    = (const float*)d_in[13];
    const float* w1     = (const float*)d_in[14];
    const float* b1     = (const float*)d_in[15];
    const float* w2     = (const float*)d_in[16];
    const float* b2     = (const float*)d_in[17];

    // workspace. o_bf region is reused by mid_bf (ffn1 output) since o_bf is
    // dead after the out-projection, which runs before ffn1.
    char* p = (char*)d_ws;
    short* h_bf   = (short*)p; p += (size_t)4096 * 512 * 2;
    short* qkv_bf = (short*)p; p += (size_t)4096 * 1536 * 2;
    float* hres   = (float*)p; p += (size_t)4096 * 512 * 4;
    short* h2_bf  = (short*)p; p += (size_t)4096 * 512 * 2;
    short* win_bf = (short*)p; p += (size_t)1536 * 512 * 2;
    short* wo_bf  = (short*)p; p += (size_t)512 * 512 * 2;
    short* w1_bf  = (short*)p; p += (size_t)2048 * 512 * 2;
    short* w2_bf  = (short*)p; p += (size_t)512 * 2048 * 2;
    short* Tg     = (short*)p; p += (size_t)8192;  // 194*16 bf16 = 6208 B
    short* o_bf   = (short*)p;
    short* mid_bf = (short*)p;  // overlays o_bf region
    p += (size_t)4096 * 2048 * 2;
    float* fpart  = (float*)p; p += (size_t)4 * 4096 * 512 * 4;  // ffn2 split-K planes

    const int M = BB * NN;  // 4096

    cvt_weights<<<dim3(512, 5), 256, 0, stream>>>(
        win, wo, w1, w2, win_bf, wo_bf, w1_bf, w2_bf, rbfw, rbfb, Tg,
        1536 * 512, 512 * 512, 2048 * 512, 512 * 2048);
    ln_kernel<<<M, 256, 0, stream>>>(x, n1g, n1b, h_bf);
    // qkv: back to the 16-MFMA/wave 128x128 structure (m97 ladder)
    gemm_bf16<128, false, 0, true, false><<<dim3(12, 32), 256, 0, stream>>>(
        h_bf, win_bf, bin, nullptr, qkv_bf, M, TD, DD, DD);
    attn_mfma<<<256, 512, 0, stream>>>(
        qkv_bf, dist, dist3d, demb, Tg, o_bf);
    gemm_bf16<32, false, 2, false, false><<<dim3(4, 128), 256, 0, stream>>>(
        o_bf, wo_bf, bo, h_bf, hres, M, DD, DD, DD);
    ln_kernel<<<M, 256, 0, stream>>>(hres, n2g, n2b, h2_bf);
    gemm_bf16<128, true, 0, true, false><<<dim3(16, 32), 256, 0, stream>>>(
        h2_bf, w1_bf, b1, nullptr, mid_bf, M, 2048, DD, DD);
    // ffn2: split-K=4 -> 512 blocks of the 128x128 structure over K=512 each,
    // fp32 partial planes + combine (bias + fp32 residual + final store).
    gemm_bf16<128, false, 0, false, true><<<dim3(4, 32, 4), 256, 0, stream>>>(
        mid_bf, w2_bf, nullptr, nullptr, fpart, M, DD, 2048, DD);
    combine4<<<2048, 256, 0, stream>>>(fpart, b2, hres, (float*)d_out);
}